// Round 23
// baseline (189.592 us; speedup 1.0000x reference)
//
#include <hip/hip_runtime.h>
#include <hip/hip_bf16.h>

// out[n,d] = b[d] + pk[n,d] + max_m ok[n,m,d]
//   pk = p @ Wp^T  (2048x1024,  K=1024)
//   ok = o @ Wo^T  (65536x1024, K=1024)
// R23 = R22 with the B-buffer toggle FIXED: STAGE_B(bcur ^ 98304, ...)
// (R22's "bcur ^ 98304 ^ 65536" == bcur ^ 32768 wrote B over the A buffer).
// 256x256 tile, 1024 thr (16 waves, 4Mx4N), LDS 96KB (A 32K @0,
// Bbuf0 @32768, Bbuf1 @65536) -> 1 block/CU = 4 waves/SIMD (same as R21),
// half the B-DMA traffic and half the barriers per output vs R21.
// Only VMEM wait: staging-top VMCNT(0), retiring full-tile-old loads.

#define NN 2048
#define MM 32
#define CC 1024

typedef __attribute__((ext_vector_type(8))) __bf16 bf16x8;
typedef __attribute__((ext_vector_type(4))) float f32x4;
typedef __attribute__((ext_vector_type(8))) unsigned short u16x8;
typedef __attribute__((ext_vector_type(4))) unsigned short u16x4;

__device__ inline unsigned short f2bf(float f) {
  union { __hip_bfloat16 h; unsigned short u; } v;
  v.h = __float2bfloat16(f);
  return v.u;
}

__device__ inline void gload_lds16(const void* g, void* l) {
  __builtin_amdgcn_global_load_lds(
      (const __attribute__((address_space(1))) void*)g,
      (__attribute__((address_space(3))) void*)l, 16, 0, 0);
}

#define BARRIER                                      \
  do {                                               \
    asm volatile("" ::: "memory");                   \
    __builtin_amdgcn_s_barrier();                    \
    asm volatile("" ::: "memory");                   \
  } while (0)

#define LGKM0 asm volatile("s_waitcnt lgkmcnt(0)" ::: "memory")
#define VMCNT(n) asm volatile("s_waitcnt vmcnt(" #n ")" ::: "memory")

// ==================== prep: Wo convert (512 blocks) + pk GEMM (128) =========
__global__ __launch_bounds__(256, 2) void prep(
    const float* __restrict__ p,      // (N, C)
    const float* __restrict__ W,      // (C, 2C)
    const float* __restrict__ bvec,   // (C,)
    unsigned short* __restrict__ wo,  // out: Wo bf16 (C x C)
    float* __restrict__ pkb) {        // out: pk + b  (N x C)
  if (blockIdx.x < 512) {
    int i = blockIdx.x * 256 + threadIdx.x;
    int e = i * 8;
    int d = e >> 10;
    int c = e & 1023;
    const float4* s = reinterpret_cast<const float4*>(W + (size_t)d * 2048 + CC + c);
    float4 a = s[0], b = s[1];
    u16x8 r;
    r[0] = f2bf(a.x); r[1] = f2bf(a.y); r[2] = f2bf(a.z); r[3] = f2bf(a.w);
    r[4] = f2bf(b.x); r[5] = f2bf(b.y); r[6] = f2bf(b.z); r[7] = f2bf(b.w);
    *reinterpret_cast<u16x8*>(wo + (size_t)d * CC + c) = r;
    return;
  }

  __shared__ char lds[32768];
  int obid = blockIdx.x - 512;
  int vb = (obid & 7) * 16 + (obid >> 3);
  int bcol = vb & 7;
  int brow = vb >> 3;

  int tid = threadIdx.x;
  int l = tid & 63;
  int wid = tid >> 6;
  int wr = wid >> 1, wc = wid & 1;
  int lr = l & 15;
  int g = l >> 4;

  const float* gP = p + (size_t)brow * 128 * CC;
  const float* gW = W + (size_t)bcol * 128 * 2048;

  int arow0 = tid >> 4;
  int ac4 = tid & 15;
  int aswz = (((ac4 >> 1) ^ (arow0 & 7)) * 16) + (ac4 & 1) * 8;

  int axor = lr & 7;
  int a_k0 = (wr * 64 + lr) * 128 + ((g ^ axor) * 16);
  int a_k1 = (wr * 64 + lr) * 128 + (((4 + g) ^ axor) * 16);
  int b_k0 = 16384 + (wc * 64 + lr) * 128 + ((g ^ axor) * 16);
  int b_k1 = 16384 + (wc * 64 + lr) * 128 + (((4 + g) ^ axor) * 16);

  f32x4 acc[4][4] = {};
  bf16x8 af[4], bfr[4];
  float4 aL[8], bL[8];

#define ISSUE_P(k0)                                                           \
  do {                                                                        \
    _Pragma("unroll") for (int j = 0; j < 8; ++j)                             \
        aL[j] = *reinterpret_cast<const float4*>(                             \
            gP + (size_t)(j * 16 + arow0) * CC + (k0) + ac4 * 4);             \
  } while (0)
#define ISSUE_W(k0)                                                           \
  do {                                                                        \
    _Pragma("unroll") for (int j = 0; j < 8; ++j)                             \
        bL[j] = *reinterpret_cast<const float4*>(                             \
            gW + (size_t)(j * 16 + arow0) * 2048 + (k0) + ac4 * 4);           \
  } while (0)
#define CVT_WR(src, base)                                                     \
  do {                                                                        \
    _Pragma("unroll") for (int j = 0; j < 8; ++j) {                           \
      u16x4 r;                                                                \
      r[0] = f2bf(src[j].x); r[1] = f2bf(src[j].y);                           \
      r[2] = f2bf(src[j].z); r[3] = f2bf(src[j].w);                           \
      *reinterpret_cast<u16x4*>(lds + (base) + (j * 16 + arow0) * 128 + aswz) = r; \
    }                                                                         \
  } while (0)
#define PK_MFMA                                                               \
  do {                                                                        \
    _Pragma("unroll") for (int mi = 0; mi < 4; ++mi)                          \
        _Pragma("unroll") for (int ni = 0; ni < 4; ++ni)                      \
            acc[mi][ni] = __builtin_amdgcn_mfma_f32_16x16x32_bf16(            \
                af[mi], bfr[ni], acc[mi][ni], 0, 0, 0);                       \
  } while (0)

  ISSUE_P(0);
  ISSUE_W(0);

#pragma unroll 1
  for (int t = 0; t < 16; ++t) {
    BARRIER;
    VMCNT(0);
    CVT_WR(aL, 0);
    CVT_WR(bL, 16384);
    if (t + 1 < 16) { ISSUE_P((t + 1) * 64); ISSUE_W((t + 1) * 64); }
    LGKM0;
    BARRIER;
#pragma unroll
    for (int mi = 0; mi < 4; ++mi)
      af[mi] = *(const bf16x8*)(lds + a_k0 + mi * 2048);
#pragma unroll
    for (int ni = 0; ni < 4; ++ni)
      bfr[ni] = *(const bf16x8*)(lds + b_k0 + ni * 2048);
    LGKM0;
    PK_MFMA;
#pragma unroll
    for (int mi = 0; mi < 4; ++mi)
      af[mi] = *(const bf16x8*)(lds + a_k1 + mi * 2048);
#pragma unroll
    for (int ni = 0; ni < 4; ++ni)
      bfr[ni] = *(const bf16x8*)(lds + b_k1 + ni * 2048);
    LGKM0;
    PK_MFMA;
  }

#pragma unroll
  for (int mi = 0; mi < 4; ++mi) {
    int row = brow * 128 + wr * 64 + mi * 16 + (l >> 4) * 4;
#pragma unroll
    for (int ni = 0; ni < 4; ++ni) {
      int col = bcol * 128 + wc * 64 + ni * 16 + lr;
      float bb = bvec[col];
#pragma unroll
      for (int r = 0; r < 4; ++r)
        pkb[(size_t)(row + r) * CC + col] = acc[mi][ni][r] + bb;
    }
  }
#undef ISSUE_P
#undef ISSUE_W
#undef CVT_WR
#undef PK_MFMA
}

// ==================== 256x256 fused GEMM, 1024 thr, B-dbuf (R23) ============
// LDS: A [256x64 bf16, 128B rows] @ 0 (32KB); Bbuf0 @ 32768; Bbuf1 @ 65536.
// Swizzle: LDS cell (row, chunk16B c) holds logical chunk c ^ (row&7).

#define STAGE_B(bo, k0)                                                       \
  do {                                                                        \
    _Pragma("unroll") for (int j = 0; j < 2; ++j)                             \
        gload_lds16(gB + (size_t)(j * 128 + brr) * CC + (k0) + bsc,           \
                    lds + (bo) + ((j * 1024 + tid) * 16));                    \
  } while (0)

#define ISSUE_A(k0)                                                           \
  do {                                                                        \
    _Pragma("unroll") for (int j = 0; j < 4; ++j)                             \
        aL[j] = *reinterpret_cast<const float4*>(                             \
            gAf + (size_t)(j * 64 + arow0) * CC + (k0) + ac4 * 4);            \
  } while (0)

#define CVT_WRITE_A                                                           \
  do {                                                                        \
    _Pragma("unroll") for (int j = 0; j < 4; ++j) {                           \
      u16x4 r;                                                                \
      r[0] = f2bf(aL[j].x); r[1] = f2bf(aL[j].y);                             \
      r[2] = f2bf(aL[j].z); r[3] = f2bf(aL[j].w);                             \
      *reinterpret_cast<u16x4*>(lds + (j * 64 + arow0) * 128 + aswz) = r;     \
    }                                                                         \
  } while (0)

#define MFMA16X                                                               \
  do {                                                                        \
    __builtin_amdgcn_s_setprio(1);                                            \
    _Pragma("unroll") for (int mi = 0; mi < 4; ++mi)                          \
        _Pragma("unroll") for (int ni = 0; ni < 4; ++ni)                      \
            acc[mi][ni] = __builtin_amdgcn_mfma_f32_16x16x32_bf16(            \
                af[mi], bfr[ni], acc[mi][ni], 0, 0, 0);                       \
    __builtin_amdgcn_s_setprio(0);                                            \
  } while (0)

__global__ __launch_bounds__(1024, 4) void gemm_fused(
    const float* __restrict__ A,
    const unsigned short* __restrict__ B,
    const float* __restrict__ pkb,
    float* __restrict__ out) {
  __shared__ char lds[98304];

  int obid = blockIdx.x;                    // 1024 blocks
  int vb = (obid & 7) * 128 + (obid >> 3);  // XCD-contiguous (1024 % 8 == 0)
  int bcol = vb & 3;                        // 4 col tiles of 256
  int brow = vb >> 2;                       // 256 row tiles of 256

  int tid = threadIdx.x;
  int l = tid & 63;
  int wid = tid >> 6;  // 0..15
  int wr = wid >> 2;   // 0..3 (M quarter, 64 rows)
  int wc = wid & 3;    // 0..3 (N quarter, 64 cols)
  int lr = l & 15;
  int g = l >> 4;      // 0..3

  const float* gAf = A + (size_t)brow * 256 * CC;
  const unsigned short* gB = B + (size_t)bcol * 256 * CC;

  // B staging: instr j -> row j*128 + brr, chunk tid&7; inverse-swz source.
  int brr = tid >> 3;                            // 0..127
  int bsc = ((tid & 7) ^ ((tid >> 3) & 7)) * 8;  // inverse-swz source col

  // A reg-staging: instr j -> row j*64+arow0, 16B f32 col ac4 (coalesced).
  int arow0 = tid >> 4;                      // 0..63  (row&7 == arow0&7)
  int ac4 = tid & 15;
  int aswz = (((ac4 >> 1) ^ (arow0 & 7)) * 16) + (ac4 & 1) * 8;

  // fragment read bases: A row = wr*64+mi*16+lr; B row = wc*64+ni*16+lr
  int axor = lr & 7;
  int a_k0 = (wr * 64 + lr) * 128 + ((g ^ axor) * 16);
  int a_k1 = (wr * 64 + lr) * 128 + (((4 + g) ^ axor) * 16);
  int b_k0r = (wc * 64 + lr) * 128 + ((g ^ axor) * 16);   // relative to B buf
  int b_k1r = (wc * 64 + lr) * 128 + (((4 + g) ^ axor) * 16);

  f32x4 acc[4][4] = {};
  bf16x8 af[4], bfr[4];
  float4 aL[4];

  // prologue: B(0) -> buf0 [2], A(0) regs [4].
  STAGE_B(32768, 0);
  ISSUE_A(0);

  int bcur = 32768;  // B buffer holding tile t (uniform); toggle = ^98304

#pragma unroll 1
  for (int t = 0; t < 16; ++t) {
    BARRIER;                 // tile t-1 LDS reads done (A + Bbuf[bcur^98304])
    VMCNT(0);                // retire A(t)+B(t): issued a FULL tile ago
    CVT_WRITE_A;             // A(t) f32 regs -> bf16 LDS (swizzled)
    if (t + 1 < 16) {
      STAGE_B(bcur ^ 98304, (t + 1) * 64);  // B(t+1) DMA -> other buf [2]
      ISSUE_A((t + 1) * 64);                // A(t+1) [4]
    }
    LGKM0;                   // our ds_writes visible
    BARRIER;                 // A(t) + B(t) LDS ready for all waves
    // compute kk=0
#pragma unroll
    for (int mi = 0; mi < 4; ++mi)
      af[mi] = *(const bf16x8*)(lds + a_k0 + mi * 2048);
#pragma unroll
    for (int ni = 0; ni < 4; ++ni)
      bfr[ni] = *(const bf16x8*)(lds + bcur + b_k0r + ni * 2048);
    LGKM0;
    MFMA16X;
    // compute kk=1
#pragma unroll
    for (int mi = 0; mi < 4; ++mi)
      af[mi] = *(const bf16x8*)(lds + a_k1 + mi * 2048);
#pragma unroll
    for (int ni = 0; ni < 4; ++ni)
      bfr[ni] = *(const bf16x8*)(lds + bcur + b_k1r + ni * 2048);
    LGKM0;
    MFMA16X;
    bcur ^= 98304;           // 32768 <-> 65536
  }

  // fused epilogue: max over 32 consecutive A-rows per n, + pkb
#pragma unroll
  for (int a = 0; a < 2; ++a) {
    int n = brow * 8 + wr * 2 + a;
#pragma unroll
    for (int ni = 0; ni < 4; ++ni) {
      float v = -3.402823466e38f;
#pragma unroll
      for (int mi = 2 * a; mi < 2 * a + 2; ++mi)
#pragma unroll
        for (int r = 0; r < 4; ++r) v = fmaxf(v, acc[mi][ni][r]);
      v = fmaxf(v, __shfl_xor(v, 16));
      v = fmaxf(v, __shfl_xor(v, 32));
      if (l < 16) {
        int col = bcol * 256 + wc * 64 + ni * 16 + l;
        out[(size_t)n * CC + col] = v + pkb[(size_t)n * CC + col];
      }
    }
  }
}

extern "C" void kernel_launch(void* const* d_in, const int* in_sizes, int n_in,
                              void* d_out, int out_size, void* d_ws, size_t ws_size,
                              hipStream_t stream) {
  const float* p = (const float*)d_in[0];   // (N, C, 1, 1)
  const float* o = (const float*)d_in[1];   // (N, M, C, 1, 1)
  const float* W = (const float*)d_in[5];   // (C, 2C)
  const float* b = (const float*)d_in[6];   // (C,)
  float* out = (float*)d_out;               // (N, C, 1, 1)

  char* ws = (char*)d_ws;
  unsigned short* wo_bf = (unsigned short*)ws;             // 2 MB
  float*          pkb   = (float*)(ws + 2097152);          // 8 MB

  // prep: blocks 0..511 convert Wo; blocks 512..639 pk GEMM (fused cvt)
  prep<<<640, 256, 0, stream>>>(p, W, b, wo_bf, pkb);
  // main: 256 row tiles x 4 col tiles = 1024 blocks, 1024 threads
  gemm_fused<<<1024, 1024, 0, stream>>>(o, wo_bf, pkb, out);
}

// Round 24
// 173.932 us; speedup vs baseline: 1.0900x; 1.0900x over previous
//
#include <hip/hip_runtime.h>
#include <hip/hip_bf16.h>

// out[n,d] = b[d] + pk[n,d] + max_m ok[n,m,d]
//   pk = p @ Wp^T  (2048x1024,  K=1024)
//   ok = o @ Wo^T  (65536x1024, K=1024)
// R24 = R21 verbatim (best measured: 169.2 us). 128x256 tile, 512 thr,
// LDS 80KB (A 16K @0, Bbuf0 32K @16384, Bbuf1 32K @49152) -> 2 blocks/CU.
// Fused A f32->bf16 convert (coalesced reg-stage -> cvt -> XOR-swizzled
// ds_write). B double-buffered via global_load_lds (inverse-swizzled src).
// The loop's ONLY vmem wait is VMCNT(0) at staging-top, retiring loads
// issued a full tile earlier. prep kernel: Wo convert + pk GEMM (fused cvt).

#define NN 2048
#define MM 32
#define CC 1024

typedef __attribute__((ext_vector_type(8))) __bf16 bf16x8;
typedef __attribute__((ext_vector_type(4))) float f32x4;
typedef __attribute__((ext_vector_type(8))) unsigned short u16x8;
typedef __attribute__((ext_vector_type(4))) unsigned short u16x4;

__device__ inline unsigned short f2bf(float f) {
  union { __hip_bfloat16 h; unsigned short u; } v;
  v.h = __float2bfloat16(f);
  return v.u;
}

__device__ inline void gload_lds16(const void* g, void* l) {
  __builtin_amdgcn_global_load_lds(
      (const __attribute__((address_space(1))) void*)g,
      (__attribute__((address_space(3))) void*)l, 16, 0, 0);
}

#define BARRIER                                      \
  do {                                               \
    asm volatile("" ::: "memory");                   \
    __builtin_amdgcn_s_barrier();                    \
    asm volatile("" ::: "memory");                   \
  } while (0)

#define LGKM0 asm volatile("s_waitcnt lgkmcnt(0)" ::: "memory")
#define VMCNT(n) asm volatile("s_waitcnt vmcnt(" #n ")" ::: "memory")

// ==================== prep: Wo convert (512 blocks) + pk GEMM (128) =========
__global__ __launch_bounds__(256, 2) void prep(
    const float* __restrict__ p,      // (N, C)
    const float* __restrict__ W,      // (C, 2C)
    const float* __restrict__ bvec,   // (C,)
    unsigned short* __restrict__ wo,  // out: Wo bf16 (C x C)
    float* __restrict__ pkb) {        // out: pk + b  (N x C)
  if (blockIdx.x < 512) {
    int i = blockIdx.x * 256 + threadIdx.x;
    int e = i * 8;
    int d = e >> 10;
    int c = e & 1023;
    const float4* s = reinterpret_cast<const float4*>(W + (size_t)d * 2048 + CC + c);
    float4 a = s[0], b = s[1];
    u16x8 r;
    r[0] = f2bf(a.x); r[1] = f2bf(a.y); r[2] = f2bf(a.z); r[3] = f2bf(a.w);
    r[4] = f2bf(b.x); r[5] = f2bf(b.y); r[6] = f2bf(b.z); r[7] = f2bf(b.w);
    *reinterpret_cast<u16x8*>(wo + (size_t)d * CC + c) = r;
    return;
  }

  __shared__ char lds[32768];
  int obid = blockIdx.x - 512;
  int vb = (obid & 7) * 16 + (obid >> 3);
  int bcol = vb & 7;
  int brow = vb >> 3;

  int tid = threadIdx.x;
  int l = tid & 63;
  int wid = tid >> 6;
  int wr = wid >> 1, wc = wid & 1;
  int lr = l & 15;
  int g = l >> 4;

  const float* gP = p + (size_t)brow * 128 * CC;
  const float* gW = W + (size_t)bcol * 128 * 2048;

  int arow0 = tid >> 4;
  int ac4 = tid & 15;
  int aswz = (((ac4 >> 1) ^ (arow0 & 7)) * 16) + (ac4 & 1) * 8;

  int axor = lr & 7;
  int a_k0 = (wr * 64 + lr) * 128 + ((g ^ axor) * 16);
  int a_k1 = (wr * 64 + lr) * 128 + (((4 + g) ^ axor) * 16);
  int b_k0 = 16384 + (wc * 64 + lr) * 128 + ((g ^ axor) * 16);
  int b_k1 = 16384 + (wc * 64 + lr) * 128 + (((4 + g) ^ axor) * 16);

  f32x4 acc[4][4] = {};
  bf16x8 af[4], bfr[4];
  float4 aL[8], bL[8];

#define ISSUE_P(k0)                                                           \
  do {                                                                        \
    _Pragma("unroll") for (int j = 0; j < 8; ++j)                             \
        aL[j] = *reinterpret_cast<const float4*>(                             \
            gP + (size_t)(j * 16 + arow0) * CC + (k0) + ac4 * 4);             \
  } while (0)
#define ISSUE_W(k0)                                                           \
  do {                                                                        \
    _Pragma("unroll") for (int j = 0; j < 8; ++j)                             \
        bL[j] = *reinterpret_cast<const float4*>(                             \
            gW + (size_t)(j * 16 + arow0) * 2048 + (k0) + ac4 * 4);           \
  } while (0)
#define CVT_WR(src, base)                                                     \
  do {                                                                        \
    _Pragma("unroll") for (int j = 0; j < 8; ++j) {                           \
      u16x4 r;                                                                \
      r[0] = f2bf(src[j].x); r[1] = f2bf(src[j].y);                           \
      r[2] = f2bf(src[j].z); r[3] = f2bf(src[j].w);                           \
      *reinterpret_cast<u16x4*>(lds + (base) + (j * 16 + arow0) * 128 + aswz) = r; \
    }                                                                         \
  } while (0)
#define PK_MFMA                                                               \
  do {                                                                        \
    _Pragma("unroll") for (int mi = 0; mi < 4; ++mi)                          \
        _Pragma("unroll") for (int ni = 0; ni < 4; ++ni)                      \
            acc[mi][ni] = __builtin_amdgcn_mfma_f32_16x16x32_bf16(            \
                af[mi], bfr[ni], acc[mi][ni], 0, 0, 0);                       \
  } while (0)

  ISSUE_P(0);
  ISSUE_W(0);

#pragma unroll 1
  for (int t = 0; t < 16; ++t) {
    BARRIER;
    VMCNT(0);
    CVT_WR(aL, 0);
    CVT_WR(bL, 16384);
    if (t + 1 < 16) { ISSUE_P((t + 1) * 64); ISSUE_W((t + 1) * 64); }
    LGKM0;
    BARRIER;
#pragma unroll
    for (int mi = 0; mi < 4; ++mi)
      af[mi] = *(const bf16x8*)(lds + a_k0 + mi * 2048);
#pragma unroll
    for (int ni = 0; ni < 4; ++ni)
      bfr[ni] = *(const bf16x8*)(lds + b_k0 + ni * 2048);
    LGKM0;
    PK_MFMA;
#pragma unroll
    for (int mi = 0; mi < 4; ++mi)
      af[mi] = *(const bf16x8*)(lds + a_k1 + mi * 2048);
#pragma unroll
    for (int ni = 0; ni < 4; ++ni)
      bfr[ni] = *(const bf16x8*)(lds + b_k1 + ni * 2048);
    LGKM0;
    PK_MFMA;
  }

#pragma unroll
  for (int mi = 0; mi < 4; ++mi) {
    int row = brow * 128 + wr * 64 + mi * 16 + (l >> 4) * 4;
#pragma unroll
    for (int ni = 0; ni < 4; ++ni) {
      int col = bcol * 128 + wc * 64 + ni * 16 + lr;
      float bb = bvec[col];
#pragma unroll
      for (int r = 0; r < 4; ++r)
        pkb[(size_t)(row + r) * CC + col] = acc[mi][ni][r] + bb;
    }
  }
#undef ISSUE_P
#undef ISSUE_W
#undef CVT_WR
#undef PK_MFMA
}

// ==================== 128x256 fused GEMM, B-dbuf (R21/R24) ==================
// LDS: A [128x64 bf16, 128B rows] @ 0 (16KB); Bbuf0 @ 16384; Bbuf1 @ 49152.
// Swizzle: LDS cell (row, chunk16B c) holds logical chunk c ^ (row&7).

#define STAGE_B(bo, k0)                                                       \
  do {                                                                        \
    _Pragma("unroll") for (int j = 0; j < 4; ++j)                             \
        gload_lds16(gB + (size_t)(j * 64 + brr) * CC + (k0) + bsc,            \
                    lds + (bo) + ((j * 512 + tid) * 16));                     \
  } while (0)

#define ISSUE_A(k0)                                                           \
  do {                                                                        \
    _Pragma("unroll") for (int j = 0; j < 4; ++j)                             \
        aL[j] = *reinterpret_cast<const float4*>(                             \
            gAf + (size_t)(j * 32 + arow0) * CC + (k0) + ac4 * 4);            \
  } while (0)

#define CVT_WRITE_A                                                           \
  do {                                                                        \
    _Pragma("unroll") for (int j = 0; j < 4; ++j) {                           \
      u16x4 r;                                                                \
      r[0] = f2bf(aL[j].x); r[1] = f2bf(aL[j].y);                             \
      r[2] = f2bf(aL[j].z); r[3] = f2bf(aL[j].w);                             \
      *reinterpret_cast<u16x4*>(lds + (j * 32 + arow0) * 128 + aswz) = r;     \
    }                                                                         \
  } while (0)

#define MFMA16X                                                               \
  do {                                                                        \
    __builtin_amdgcn_s_setprio(1);                                            \
    _Pragma("unroll") for (int mi = 0; mi < 4; ++mi)                          \
        _Pragma("unroll") for (int ni = 0; ni < 4; ++ni)                      \
            acc[mi][ni] = __builtin_amdgcn_mfma_f32_16x16x32_bf16(            \
                af[mi], bfr[ni], acc[mi][ni], 0, 0, 0);                       \
    __builtin_amdgcn_s_setprio(0);                                            \
  } while (0)

__global__ __launch_bounds__(512, 4) void gemm_fused(
    const float* __restrict__ A,
    const unsigned short* __restrict__ B,
    const float* __restrict__ pkb,
    float* __restrict__ out) {
  __shared__ char lds[81920];

  int obid = blockIdx.x;                    // 2048 blocks
  int vb = (obid & 7) * 256 + (obid >> 3);  // XCD-contiguous (2048 % 8 == 0)
  int bcol = vb & 3;                        // 4 col tiles of 256
  int brow = vb >> 2;                       // 512 row tiles of 128

  int tid = threadIdx.x;
  int l = tid & 63;
  int wid = tid >> 6;  // 0..7
  int wr = wid >> 2;   // 0..1 (M half, 64 rows)
  int wc = wid & 3;    // 0..3 (N quarter, 64 cols)
  int lr = l & 15;
  int g = l >> 4;      // 0..3

  const float* gAf = A + (size_t)brow * 128 * CC;
  const unsigned short* gB = B + (size_t)bcol * 256 * CC;

  int brr = tid >> 3;                            // 0..63
  int bsc = ((tid & 7) ^ ((tid >> 3) & 7)) * 8;  // inverse-swz source col

  int arow0 = tid >> 4;                      // 0..31  (row&7 == arow0&7)
  int ac4 = tid & 15;
  int aswz = (((ac4 >> 1) ^ (arow0 & 7)) * 16) + (ac4 & 1) * 8;

  int axor = lr & 7;
  int a_k0 = (wr * 64 + lr) * 128 + ((g ^ axor) * 16);
  int a_k1 = (wr * 64 + lr) * 128 + (((4 + g) ^ axor) * 16);
  int b_k0r = (wc * 64 + lr) * 128 + ((g ^ axor) * 16);   // relative to B buf
  int b_k1r = (wc * 64 + lr) * 128 + (((4 + g) ^ axor) * 16);

  f32x4 acc[4][4] = {};
  bf16x8 af[4], bfr[4];
  float4 aL[4];

  // prologue: B(0) -> buf0, A(0) regs. Outstanding = [B(0):4, A(0):4].
  STAGE_B(16384, 0);
  ISSUE_A(0);

  int bcur = 16384;  // B buffer holding tile t (uniform); toggle = ^32768

#pragma unroll 1
  for (int t = 0; t < 16; ++t) {
    BARRIER;                 // tile t-1 LDS reads done (A + Bbuf[cur^32768])
    VMCNT(0);                // retire A(t)+B(t): issued a FULL tile ago
    CVT_WRITE_A;             // A(t) f32 regs -> bf16 LDS (swizzled)
    if (t + 1 < 16) {
      STAGE_B(bcur ^ 32768, (t + 1) * 64);  // B(t+1) DMA -> other buf [4]
      ISSUE_A((t + 1) * 64);                // A(t+1) [4]
    }
    LGKM0;                   // our ds_writes visible
    BARRIER;                 // A(t) + B(t) LDS ready for all waves
    // compute kk=0
#pragma unroll
    for (int mi = 0; mi < 4; ++mi)
      af[mi] = *(const bf16x8*)(lds + a_k0 + mi * 2048);
#pragma unroll
    for (int ni = 0; ni < 4; ++ni)
      bfr[ni] = *(const bf16x8*)(lds + bcur + b_k0r + ni * 2048);
    LGKM0;
    MFMA16X;
    // compute kk=1
#pragma unroll
    for (int mi = 0; mi < 4; ++mi)
      af[mi] = *(const bf16x8*)(lds + a_k1 + mi * 2048);
#pragma unroll
    for (int ni = 0; ni < 4; ++ni)
      bfr[ni] = *(const bf16x8*)(lds + bcur + b_k1r + ni * 2048);
    LGKM0;
    MFMA16X;
    bcur ^= 32768;
  }

  // fused epilogue: max over 32 consecutive A-rows per n, + pkb
#pragma unroll
  for (int a = 0; a < 2; ++a) {
    int n = brow * 4 + wr * 2 + a;
#pragma unroll
    for (int ni = 0; ni < 4; ++ni) {
      float v = -3.402823466e38f;
#pragma unroll
      for (int mi = 2 * a; mi < 2 * a + 2; ++mi)
#pragma unroll
        for (int r = 0; r < 4; ++r) v = fmaxf(v, acc[mi][ni][r]);
      v = fmaxf(v, __shfl_xor(v, 16));
      v = fmaxf(v, __shfl_xor(v, 32));
      if (l < 16) {
        int col = bcol * 256 + wc * 64 + ni * 16 + l;
        out[(size_t)n * CC + col] = v + pkb[(size_t)n * CC + col];
      }
    }
  }
}

extern "C" void kernel_launch(void* const* d_in, const int* in_sizes, int n_in,
                              void* d_out, int out_size, void* d_ws, size_t ws_size,
                              hipStream_t stream) {
  const float* p = (const float*)d_in[0];   // (N, C, 1, 1)
  const float* o = (const float*)d_in[1];   // (N, M, C, 1, 1)
  const float* W = (const float*)d_in[5];   // (C, 2C)
  const float* b = (const float*)d_in[6];   // (C,)
  float* out = (float*)d_out;               // (N, C, 1, 1)

  char* ws = (char*)d_ws;
  unsigned short* wo_bf = (unsigned short*)ws;             // 2 MB
  float*          pkb   = (float*)(ws + 2097152);          // 8 MB

  // prep: blocks 0..511 convert Wo; blocks 512..639 pk GEMM (fused cvt)
  prep<<<640, 256, 0, stream>>>(p, W, b, wo_bf, pkb);
  // main: 512 row tiles x 4 col tiles = 2048 blocks, 512 threads
  gemm_fused<<<2048, 512, 0, stream>>>(o, wo_bf, pkb, out);
}